// Round 5
// baseline (425.890 us; speedup 1.0000x reference)
//
#include <hip/hip_runtime.h>
#include <stdint.h>

typedef __attribute__((ext_vector_type(4))) float  floatx4;   // MFMA C/D frag
typedef __attribute__((ext_vector_type(8))) short  shortx8;   // MFMA A/B frag (8 bf16)
typedef __attribute__((ext_vector_type(4))) unsigned short ushortx4;

typedef unsigned int   u32;
typedef unsigned short u16;

#define TILE    128
#define BK      64
#define THREADS 256
#define CHUNK   (TILE * BK)

// ---- bf16 pack: +0x8000 round, take high halves via v_perm ----
__device__ __forceinline__ u32 pack2bf(float f0, float f1) {
    u32 u0 = __builtin_bit_cast(u32, f0) + 0x8000u;
    u32 u1 = __builtin_bit_cast(u32, f1) + 0x8000u;
    return __builtin_amdgcn_perm(u1, u0, 0x07060302u);
}

__device__ __forceinline__ unsigned short f2bf(float f) {
    u32 u = __builtin_bit_cast(u32, f);
    u += 0x7FFFu + ((u >> 16) & 1u);
    return (unsigned short)(u >> 16);
}

// ============ prep (grid-stride, fully streaming): linear-in, linear-out ============
__global__ __launch_bounds__(THREADS)
void prep_kernel(const float* __restrict__ x, const int* __restrict__ pw,
                 const float* __restrict__ scale, const int* __restrict__ pzp,
                 u16* __restrict__ At, u16* __restrict__ Bt,
                 int M, int O, int I, int ng, int lsSeg, int lsG) {
    const int NT = gridDim.x * THREADS;
    const int t0 = blockIdx.x * THREADS + threadIdx.x;
    const int segsPerRow = I >> 3;

    const int Sx = (M * I) >> 3;
    for (int s = t0; s < Sx; s += NT) {
        const float4 v0 = ((const float4*)x)[(size_t)s * 2];
        const float4 v1 = ((const float4*)x)[(size_t)s * 2 + 1];
        u32 p[4];
        p[0] = pack2bf(v0.x, v0.y); p[1] = pack2bf(v0.z, v0.w);
        p[2] = pack2bf(v1.x, v1.y); p[3] = pack2bf(v1.z, v1.w);
        ((uint4*)At)[s] = *(uint4*)p;
    }

    const int Sw = (O * I) >> 3;
    for (int s = t0; s < Sw; s += NT) {
        const u32 wq = (u32)pw[s];
        const int o    = s >> lsSeg;
        const int wcol = s & (segsPerRow - 1);
        const int g    = wcol >> lsG;
        const float sc = scale[o * ng + g];
        const int zpw  = pzp[o * ((ng + 7) >> 3) + (g >> 3)];
        const int zp   = (zpw >> ((g & 7) * 4)) & 15;
        const float nzc = -sc * (float)(zp + 128);
        float v[8];
        #pragma unroll
        for (int j = 0; j < 8; j++) {
            u32 tt;
            if (j < 4)       tt = (wq << (16 - 4 * j)) & 0x000F0000u;
            else if (j == 4) tt = wq & 0x000F0000u;
            else             tt = (wq >> (4 * j - 16)) & 0x000F0000u;
            v[j] = __builtin_fmaf(__builtin_bit_cast(float, tt | 0x43000000u), sc, nzc);
        }
        u32 p[4];
        p[0] = pack2bf(v[0], v[1]); p[1] = pack2bf(v[2], v[3]);
        p[2] = pack2bf(v[4], v[5]); p[3] = pack2bf(v[6], v[7]);
        ((uint4*)Bt)[s] = *(uint4*)p;
    }
}

// =================== 256x256 quadrant-phase GEMM (m201-style schedule) ===================
// LDS: S[buf2][half2][mat2][128 rows][64 k] bf16 = 128 KiB. Within a (buf,half,mat) block:
// row stride 128 B = 8 chunks of 16 B; chunk k stored at slot k ^ (row&7) (swizzle carried
// on the per-lane GLOBAL source address; LDS dest lane-linear for global_load_lds).
// Wave (wm in 2, wn in 4) owns C rows {qm*128 + wm*64 + [0,64)} x cols {qn*128 + wn*32 + [0,32)}
// over quadrants qm,qn in {0,1} -> quadrant qX touches only half qX of A/B.
// Window T (buffer T&1), 4 phases, each: [issue ds_reads for NEXT phase][stage one 16KB
// half of tile T+1][BAR][counted lgkmcnt (drains prev phase's reads only)][sched_barrier]
// [setprio1; 16 MFMA; setprio0][counted vmcnt][BAR].
//   reads/phase: ph1: A1(8)  ph2: B1(4)  ph3: 0  ph4: next A0+B0 (12, pre-BAR lgkm(8))
//   stages:      ph1: Ah0+Bh0 (4 gll)  ph2: Ah1  ph3: Bh1  ph4: none
//   waits:       lgkm(8)/lgkm(4)/lgkm(0)/none ; vmcnt(4)/(4)/(4)/(2)  -- never 0 in loop.
// Residency/WAR proven by FIFO simulation: each wait retires exactly the half needed by the
// next phase's reads (issued >=3 phases ~2k cyc earlier -> non-stalling); each buffer is
// re-staged >=2 barriers after its last ds_read; vmcnt-before-barrier makes staged data
// visible cross-wave before any wave reads it.

#define BARR  __builtin_amdgcn_s_barrier()
#define SCB0  __builtin_amdgcn_sched_barrier(0)
#define PRI1  __builtin_amdgcn_s_setprio(1)
#define PRI0  __builtin_amdgcn_s_setprio(0)
#define LGKM(N) asm volatile("s_waitcnt lgkmcnt(" #N ")" ::: "memory")
#define VMC(N)  asm volatile("s_waitcnt vmcnt(" #N ")" ::: "memory")

#define GLL(GP, LP)                                                                        \
    __builtin_amdgcn_global_load_lds((const __attribute__((address_space(1))) u32*)(GP),   \
        (__attribute__((address_space(3))) u32*)(LP), 16, 0, 0)

// stage one 16KB half-matrix (2 gll/thread) of tile T+1 into LDS block base LB (u16 units)
#define STGA(HOFFE, LB) do { GLL(pA0 + (HOFFE), S + (LB) + tid * 8);                       \
                             GLL(pA1 + (HOFFE), S + (LB) + 4096 + tid * 8); } while (0)
#define STGB(HOFFE, LB) do { GLL(pB0 + (HOFFE), S + (LB) + tid * 8);                       \
                             GLL(pB1 + (HOFFE), S + (LB) + 4096 + tid * 8); } while (0)

#define RDA(DST, BUF, H) do { _Pragma("unroll")                                            \
    for (int i = 0; i < 4; i++) {                                                          \
        DST[i][0] = *(const shortx8*)(S + (BUF)*32768 + (H)*16384 + aoff + i*1024 + c0);   \
        DST[i][1] = *(const shortx8*)(S + (BUF)*32768 + (H)*16384 + aoff + i*1024 + c1);   \
    } } while (0)
#define RDB(DST, BUF, H) do { _Pragma("unroll")                                            \
    for (int j = 0; j < 2; j++) {                                                          \
        DST[j][0] = *(const shortx8*)(S + (BUF)*32768 + (H)*16384 + 8192 + boff + j*1024 + c0); \
        DST[j][1] = *(const shortx8*)(S + (BUF)*32768 + (H)*16384 + 8192 + boff + j*1024 + c1); \
    } } while (0)

#define MFQ(AR, BR, RO, CO) do { _Pragma("unroll")                                         \
    for (int i = 0; i < 4; i++) { _Pragma("unroll")                                        \
        for (int j = 0; j < 2; j++) {                                                      \
            acc[(RO)+i][(CO)+j] = __builtin_amdgcn_mfma_f32_16x16x32_bf16(                 \
                AR[i][0], BR[j][0], acc[(RO)+i][(CO)+j], 0, 0, 0);                         \
            acc[(RO)+i][(CO)+j] = __builtin_amdgcn_mfma_f32_16x16x32_bf16(                 \
                AR[i][1], BR[j][1], acc[(RO)+i][(CO)+j], 0, 0, 0);                         \
        } } } while (0)

#define WINDOW(BUF, DOSTG, LAST, W1S, W4S) do {                                            \
    /* ph1: read A1(cur tile); stage next Ah0+Bh0; MFMA Q00 = a0 x b0 */                   \
    RDA(a1, BUF, 1);                                                                       \
    if (DOSTG) { STGA(0, ((BUF)^1)*32768);                                                 \
                 STGB(0, ((BUF)^1)*32768 + 8192); }                                        \
    BARR; LGKM(8); SCB0; PRI1; MFQ(a0, b0, 0, 0); PRI0; W1S; BARR;                         \
    /* ph2: read B1(cur); stage Ah1; MFMA Q10 = a1 x b0 */                                 \
    RDB(b1, BUF, 1);                                                                       \
    if (DOSTG) STGA(hOff, ((BUF)^1)*32768 + 16384);                                        \
    BARR; LGKM(4); SCB0; PRI1; MFQ(a1, b0, 4, 0); PRI0; VMC(4); BARR;                      \
    /* ph3: stage Bh1; MFMA Q01 = a0 x b1 */                                               \
    if (DOSTG) STGB(hOff, ((BUF)^1)*32768 + 16384 + 8192);                                 \
    BARR; LGKM(0); SCB0; PRI1; MFQ(a0, b1, 0, 2); PRI0; VMC(4); BARR;                      \
    /* ph4: read next tile A0+B0; MFMA Q11 = a1 x b1 */                                    \
    if (!(LAST)) { RDA(a0, (BUF)^1, 0); RDB(b0, (BUF)^1, 0); LGKM(8); }                    \
    BARR; SCB0; PRI1; MFQ(a1, b1, 4, 2); PRI0; W4S; BARR;                                  \
    if (DOSTG) { pA0 += 64; pA1 += 64; pB0 += 64; pB1 += 64; }                             \
} while (0)

__global__ __launch_bounds__(512, 2)
void gemm256(const u16* __restrict__ At, const u16* __restrict__ Bt,
             const float* __restrict__ bias, float* __restrict__ out,
             int O, int I, int KT) {
    __shared__ u16 S[65536];              // 128 KiB

    const int tid = threadIdx.x;
    const int nblk_n = O / 256;

    // bijective XCD swizzle
    int bid = blockIdx.x;
    const int nwg = gridDim.x;
    if ((nwg & 7) == 0) {
        const int q = nwg >> 3;
        bid = (bid & 7) * q + (bid >> 3);
    }
    const int mt = bid / nblk_n, nt = bid % nblk_n;

    const int w = tid >> 6, lane = tid & 63;
    const int wm = w >> 2, wn = w & 3;        // 2x4 wave grid
    const int l15 = lane & 15, l4 = lane >> 4;
    const int sw  = l15 & 7;

    // frag read offsets (u16 units) within a (buf,half,mat) block; row stride 64 u16
    const int aoff = (wm * 64 + l15) * 64;
    const int boff = (wn * 32 + l15) * 64;
    const int c0 = ((0 * 4 + l4) ^ sw) * 8;   // chunk for ks=0
    const int c1 = ((1 * 4 + l4) ^ sw) * 8;   // chunk for ks=1

    // staging map: thread t, sub-unit s: slot = s*512+t -> row = slot>>3, logical chunk
    // k = (slot&7) ^ (row&7); global source carries the swizzle, LDS dest lane-linear.
    const int rs = tid >> 3;
    const int ks = (tid & 7) ^ (rs & 7);
    const u16* pA0 = At + ((size_t)(mt * 256) + rs) * I + ks * 8;
    const u16* pA1 = pA0 + (size_t)64 * I;    // rows +64 (s=1), same k (64 = 0 mod 8)
    const u16* pB0 = Bt + ((size_t)(nt * 256) + rs) * I + ks * 8;
    const u16* pB1 = pB0 + (size_t)64 * I;
    const size_t hOff = (size_t)128 * I;      // half 1 row offset

    floatx4 acc[8][4];
    #pragma unroll
    for (int i = 0; i < 8; i++)
        #pragma unroll
        for (int j = 0; j < 4; j++)
            acc[i][j] = (floatx4){0.f, 0.f, 0.f, 0.f};

    shortx8 a0[4][2], a1[4][2], b0[2][2], b1[2][2];

    // prologue: stage tile 0 (4 halves), drain, then issue window0.ph1's operands (A0,B0)
    STGA(0, 0);               // Ah0 -> (buf0,h0,A)
    STGB(0, 8192);            // Bh0
    STGA(hOff, 16384);        // Ah1
    STGB(hOff, 16384 + 8192); // Bh1
    pA0 += 64; pA1 += 64; pB0 += 64; pB1 += 64;
    VMC(0);
    BARR;
    RDA(a0, 0, 0);
    RDB(b0, 0, 0);            // 12 reads; drained by window0.ph1's LGKM(8)

    const int pairs = (KT - 2) >> 1;
    #pragma unroll 1
    for (int t2 = 0; t2 < pairs; ++t2) {
        WINDOW(0, 1, 0, VMC(4), VMC(2));
        WINDOW(1, 1, 0, VMC(4), VMC(2));
    }
    WINDOW(0, 1, 0, VMC(4), VMC(2));      // T = KT-2: stages tile KT-1
    WINDOW(1, 0, 1, VMC(0), (void)0);     // T = KT-1: drain

    // epilogue: C rows = qm*128 + wm*64 + (i&3)*16 + l4*4 + r ; cols = qn*128 + wn*32 + (j&1)*16 + l15
    #pragma unroll
    for (int j = 0; j < 4; j++) {
        int col  = nt * 256 + (j >> 1) * 128 + wn * 32 + (j & 1) * 16 + l15;
        float bv = bias[col];
        #pragma unroll
        for (int i = 0; i < 8; i++) {
            int rowb = mt * 256 + (i >> 2) * 128 + wm * 64 + (i & 3) * 16 + l4 * 4;
            #pragma unroll
            for (int r = 0; r < 4; r++)
                out[(size_t)(rowb + r) * O + col] = acc[i][j][r] + bv;
        }
    }
}

// ============ 128x128 single-buffer GEMM (shape fallback, proven 130 us) ============
__global__ __launch_bounds__(THREADS, 2)
void gemm_bf16(const u16* __restrict__ At, const u16* __restrict__ Bt,
               const float* __restrict__ bias, float* __restrict__ out,
               int O, int I, int KT) {
    __shared__ u16 As[CHUNK];
    __shared__ u16 Bs[CHUNK];

    const int tid = threadIdx.x;
    const int nblk_n = O / TILE;
    const int mt = blockIdx.x / nblk_n;
    const int nt = blockIdx.x % nblk_n;
    const int w = tid >> 6, lane = tid & 63;
    const int wm = w >> 1, wn = w & 1;
    const int l15 = lane & 15, l4 = lane >> 4;
    const int sw  = l15 & 7;

    const int sr = tid >> 3;
    const int sc = (tid & 7) ^ (sr & 7);

    floatx4 acc[4][4];
    #pragma unroll
    for (int i = 0; i < 4; i++)
        #pragma unroll
        for (int j = 0; j < 4; j++)
            acc[i][j] = (floatx4){0.f, 0.f, 0.f, 0.f};

    const u16* gaBase = At + ((size_t)(mt * TILE) + sr) * I + sc * 8;
    const u16* gbBase = Bt + ((size_t)(nt * TILE) + sr) * I + sc * 8;

    for (int kt = 0; kt < KT; kt++) {
        const u16* ga = gaBase + kt * BK;
        const u16* gb = gbBase + kt * BK;
        __syncthreads();
        #pragma unroll
        for (int it = 0; it < 4; it++) {
            const int ldsOff = it * 2048 + tid * 8;
            const size_t gOff = (size_t)(it * 32) * I;
            GLL(ga + gOff, As + ldsOff);
            GLL(gb + gOff, Bs + ldsOff);
        }
        __syncthreads();

        #pragma unroll
        for (int kss = 0; kss < 2; kss++) {
            shortx8 af[4], bfr2[4];
            #pragma unroll
            for (int i = 0; i < 4; i++)
                af[i] = *(const shortx8*)(&As[(wm * 64 + i * 16 + l15) * BK + ((kss * 4 + l4) ^ sw) * 8]);
            #pragma unroll
            for (int j = 0; j < 4; j++)
                bfr2[j] = *(const shortx8*)(&Bs[(wn * 64 + j * 16 + l15) * BK + ((kss * 4 + l4) ^ sw) * 8]);
            #pragma unroll
            for (int i = 0; i < 4; i++)
                #pragma unroll
                for (int j = 0; j < 4; j++)
                    acc[i][j] = __builtin_amdgcn_mfma_f32_16x16x32_bf16(af[i], bfr2[j], acc[i][j], 0, 0, 0);
        }
    }

    #pragma unroll
    for (int j = 0; j < 4; j++) {
        int col  = nt * TILE + wn * 64 + j * 16 + l15;
        float bv = bias[col];
        #pragma unroll
        for (int i = 0; i < 4; i++) {
            int rowb = mt * TILE + wm * 64 + i * 16 + l4 * 4;
            #pragma unroll
            for (int r = 0; r < 4; r++)
                out[(size_t)(rowb + r) * O + col] = acc[i][j][r] + bv;
        }
    }
}

// ======================= fallback (fused) if ws too small =======================
#define LDA 72
__global__ __launch_bounds__(THREADS, 2)
void wql_fused(const float* __restrict__ x, const int* __restrict__ pw,
               const float* __restrict__ scale, const int* __restrict__ pzp,
               const float* __restrict__ bias, float* __restrict__ out,
               int M, int O, int I, int ng)
{
    __shared__ unsigned short As[TILE * LDA];
    __shared__ unsigned short Bs[TILE * LDA];
    const int tid = threadIdx.x;
    const int nblk_n = O / TILE;
    const int mt = blockIdx.x / nblk_n, nt = blockIdx.x % nblk_n;
    const int w = tid >> 6, lane = tid & 63;
    const int wm = w >> 1, wn = w & 1;
    const int l15 = lane & 15, l4 = lane >> 4;
    const int pw_rowlen = I / 8, zp_rowlen = (ng + 7) / 8, GS = I / ng;

    floatx4 acc[4][4];
    #pragma unroll
    for (int i = 0; i < 4; i++)
        #pragma unroll
        for (int j = 0; j < 4; j++) acc[i][j] = (floatx4){0.f, 0.f, 0.f, 0.f};

    const int nk = I / BK;
    for (int kt = 0; kt < nk; kt++) {
        __syncthreads();
        #pragma unroll
        for (int it = 0; it < 8; it++) {
            int f = tid + it * THREADS;
            int row = f >> 4, seg = f & 15;
            const float4 v = *(const float4*)(x + (size_t)(mt * TILE + row) * I + kt * BK + seg * 4);
            ushortx4 b;
            b.x = f2bf(v.x); b.y = f2bf(v.y); b.z = f2bf(v.z); b.w = f2bf(v.w);
            *(ushortx4*)(&As[row * LDA + seg * 4]) = b;
        }
        const int g = (kt * BK) / GS;
        #pragma unroll
        for (int it = 0; it < 4; it++) {
            int e = tid + it * THREADS;
            int row = e >> 3, c = e & 7;
            int o = nt * TILE + row;
            int wq = pw[(size_t)o * pw_rowlen + kt * (BK / 8) + c];
            float s = scale[o * ng + g];
            int zpw = pzp[o * zp_rowlen + (g >> 3)];
            int zp = (zpw >> ((g & 7) * 4)) & 15;
            shortx8 b;
            #pragma unroll
            for (int j = 0; j < 8; j++) {
                int nib = (wq >> (4 * j)) & 15;
                b[j] = (short)f2bf((float)(nib - zp) * s);
            }
            *(shortx8*)(&Bs[row * LDA + c * 8]) = b;
        }
        __syncthreads();
        #pragma unroll
        for (int kss = 0; kss < 2; kss++) {
            shortx8 af[4], bfr2[4];
            #pragma unroll
            for (int i = 0; i < 4; i++)
                af[i] = *(const shortx8*)(&As[(wm * 64 + i * 16 + l15) * LDA + kss * 32 + l4 * 8]);
            #pragma unroll
            for (int j = 0; j < 4; j++)
                bfr2[j] = *(const shortx8*)(&Bs[(wn * 64 + j * 16 + l15) * LDA + kss * 32 + l4 * 8]);
            #pragma unroll
            for (int i = 0; i < 4; i++)
                #pragma unroll
                for (int j = 0; j < 4; j++)
                    acc[i][j] = __builtin_amdgcn_mfma_f32_16x16x32_bf16(af[i], bfr2[j], acc[i][j], 0, 0, 0);
        }
    }
    #pragma unroll
    for (int j = 0; j < 4; j++) {
        int col = nt * TILE + wn * 64 + j * 16 + l15;
        float bv = bias[col];
        #pragma unroll
        for (int i = 0; i < 4; i++) {
            int rowb = mt * TILE + wm * 64 + i * 16 + l4 * 4;
            #pragma unroll
            for (int r = 0; r < 4; r++)
                out[(size_t)(rowb + r) * O + col] = acc[i][j][r] + bv;
        }
    }
}

extern "C" void kernel_launch(void* const* d_in, const int* in_sizes, int n_in,
                              void* d_out, int out_size, void* d_ws, size_t ws_size,
                              hipStream_t stream) {
    const float* x     = (const float*)d_in[0];
    const int*   pw    = (const int*)d_in[1];
    const float* scale = (const float*)d_in[2];
    const int*   pzp   = (const int*)d_in[3];
    const float* bias  = (const float*)d_in[4];
    float*       out   = (float*)d_out;

    const int O  = in_sizes[4];                   // 4096
    const int ng = in_sizes[2] / O;               // 32
    const int I  = (in_sizes[1] / O) * 8;         // 4096
    const int M  = in_sizes[0] / I;               // 4096
    int lsSeg = 0; { int v = I >> 3; while ((1 << lsSeg) < v) lsSeg++; }
    int lsG = 0;   { int v = (I / ng) >> 3; while ((1 << lsG) < v) lsG++; }

    const size_t need = ((size_t)M * I + (size_t)O * I) * sizeof(u16);  // 64 MB
    if (ws_size >= need) {
        u16* At = (u16*)d_ws;
        u16* Bt = At + (size_t)M * I;
        prep_kernel<<<dim3(2048), THREADS, 0, stream>>>(x, pw, scale, pzp, At, Bt, M, O, I, ng, lsSeg, lsG);
        const int KT64 = I / 64;
        const bool ok256 = (M % 256 == 0) && (O % 256 == 0) && (I % 128 == 0) && (KT64 >= 4);
        if (ok256) {
            gemm256<<<dim3((M / 256) * (O / 256)), 512, 0, stream>>>(At, Bt, bias, out, O, I, KT64);
        } else {
            gemm_bf16<<<dim3((M / TILE) * (O / TILE)), THREADS, 0, stream>>>(At, Bt, bias, out, O, I, I / BK);
        }
    } else {
        wql_fused<<<dim3((M / TILE) * (O / TILE)), THREADS, 0, stream>>>(x, pw, scale, pzp, bias, out, M, O, I, ng);
    }
}

// Round 7
// 375.334 us; speedup vs baseline: 1.1347x; 1.1347x over previous
//
#include <hip/hip_runtime.h>
#include <stdint.h>

typedef __attribute__((ext_vector_type(4)))  float  floatx4;    // 16x16 MFMA C/D frag
typedef __attribute__((ext_vector_type(16))) float  floatx16;   // 32x32 MFMA C/D frag
typedef __attribute__((ext_vector_type(8)))  short  shortx8;    // MFMA A/B frag (8 bf16)
typedef __attribute__((ext_vector_type(4)))  unsigned short ushortx4;

typedef unsigned int   u32;
typedef unsigned short u16;

#define TILE    128
#define BK      64
#define THREADS 256
#define CHUNK   (TILE * BK)

// ---- bf16 pack: +0x8000 round, take high halves via v_perm ----
__device__ __forceinline__ u32 pack2bf(float f0, float f1) {
    u32 u0 = __builtin_bit_cast(u32, f0) + 0x8000u;
    u32 u1 = __builtin_bit_cast(u32, f1) + 0x8000u;
    return __builtin_amdgcn_perm(u1, u0, 0x07060302u);
}

__device__ __forceinline__ unsigned short f2bf(float f) {
    u32 u = __builtin_bit_cast(u32, f);
    u += 0x7FFFu + ((u >> 16) & 1u);
    return (unsigned short)(u >> 16);
}

// ============ prep (grid-stride, fully streaming): linear-in, linear-out ============
__global__ __launch_bounds__(THREADS)
void prep_kernel(const float* __restrict__ x, const int* __restrict__ pw,
                 const float* __restrict__ scale, const int* __restrict__ pzp,
                 u16* __restrict__ At, u16* __restrict__ Bt,
                 int M, int O, int I, int ng, int lsSeg, int lsG) {
    const int NT = gridDim.x * THREADS;
    const int t0 = blockIdx.x * THREADS + threadIdx.x;
    const int segsPerRow = I >> 3;

    const int Sx = (M * I) >> 3;
    for (int s = t0; s < Sx; s += NT) {
        const float4 v0 = ((const float4*)x)[(size_t)s * 2];
        const float4 v1 = ((const float4*)x)[(size_t)s * 2 + 1];
        u32 p[4];
        p[0] = pack2bf(v0.x, v0.y); p[1] = pack2bf(v0.z, v0.w);
        p[2] = pack2bf(v1.x, v1.y); p[3] = pack2bf(v1.z, v1.w);
        ((uint4*)At)[s] = *(uint4*)p;
    }

    const int Sw = (O * I) >> 3;
    for (int s = t0; s < Sw; s += NT) {
        const u32 wq = (u32)pw[s];
        const int o    = s >> lsSeg;
        const int wcol = s & (segsPerRow - 1);
        const int g    = wcol >> lsG;
        const float sc = scale[o * ng + g];
        const int zpw  = pzp[o * ((ng + 7) >> 3) + (g >> 3)];
        const int zp   = (zpw >> ((g & 7) * 4)) & 15;
        const float nzc = -sc * (float)(zp + 128);
        float v[8];
        #pragma unroll
        for (int j = 0; j < 8; j++) {
            u32 tt;
            if (j < 4)       tt = (wq << (16 - 4 * j)) & 0x000F0000u;
            else if (j == 4) tt = wq & 0x000F0000u;
            else             tt = (wq >> (4 * j - 16)) & 0x000F0000u;
            v[j] = __builtin_fmaf(__builtin_bit_cast(float, tt | 0x43000000u), sc, nzc);
        }
        u32 p[4];
        p[0] = pack2bf(v[0], v[1]); p[1] = pack2bf(v[2], v[3]);
        p[2] = pack2bf(v[4], v[5]); p[3] = pack2bf(v[6], v[7]);
        ((uint4*)Bt)[s] = *(uint4*)p;
    }
}

// ============ 256x256 register-pipelined GEMM, 4-buffer ring, 32x32x16 MFMA ============
// Identical staging/swizzle/ring/waits to the proven round-3 kernel; only the fragment
// addressing, MFMA shape (32x32x16, -17% matrix-pipe floor per m119), and epilogue C/D
// mapping (col=lane&31, row=(reg&3)+8*(reg>>2)+4*(lane>>5); m74/m101) changed.
// LDS buffer = 256 rows x 128 B; row = [A chunks 0-3 | B chunks 0-3] of 16 B, chunk k
// stored at slot k ^ (row&7); swizzle carried on the per-lane GLOBAL source address.
// Ring: compute tile t from buf t&3 while staging tile t+3 into buf (t+3)&3.
// Register pipeline: R1 {read A row-blocks 0,1 + all B of tile T; DMA 0,1; MFMA blocks
// 2,3 of tile T-1}; R2 {read A blocks 2,3; DMA 2,3; MFMA blocks 0,1 of tile T; tile-end
// counted waitcnt (vmcnt never 0 in loop; lgkmcnt(0) closes the ring WAR); barrier}.

#define VM8L asm volatile("s_waitcnt vmcnt(8) lgkmcnt(0)" ::: "memory")
#define VM4L asm volatile("s_waitcnt vmcnt(4) lgkmcnt(0)" ::: "memory")
#define VM0L asm volatile("s_waitcnt vmcnt(0) lgkmcnt(0)" ::: "memory")

#define ISSUE(GP, NB, LO)                                                                  \
    __builtin_amdgcn_global_load_lds((const __attribute__((address_space(1))) u32*)(GP),   \
        (__attribute__((address_space(3))) u32*)((NB) + (LO)), 16, 0, 0)

#define MF32(A, B, C) __builtin_amdgcn_mfma_f32_32x32x16_bf16(A, B, C, 0, 0, 0)

// R1 of tile T (buf BUFC, parity P): read aflo (A row-blocks 0,1 x k-halves) + bfr (B
// col-blocks 0,1 x k-halves); issue DMA 0,1 for tile T+3; MFMA row-blocks 2,3 of T-1.
#define R1(BUFC, BUFN, P, DOISS, DOMFMA) do {                                              \
    const u16* __restrict__ sb = S + (BUFC) * 16384;                                       \
    u16* nb = S + (BUFN) * 16384;                                                          \
    aflo[P][0] = *(const shortx8*)(sb + aBase + cA0);                                      \
    aflo[P][1] = *(const shortx8*)(sb + aBase + cA1);                                      \
    aflo[P][2] = *(const shortx8*)(sb + aBase + 2048 + cA0);                               \
    aflo[P][3] = *(const shortx8*)(sb + aBase + 2048 + cA1);                               \
    bfr[P][0]  = *(const shortx8*)(sb + bBase + cB0);                                      \
    bfr[P][1]  = *(const shortx8*)(sb + bBase + cB1);                                      \
    bfr[P][2]  = *(const shortx8*)(sb + bBase + 2048 + cB0);                               \
    bfr[P][3]  = *(const shortx8*)(sb + bBase + 2048 + cB1);                               \
    if (DOISS) { ISSUE(g[0], nb, ldsoff[0]); ISSUE(g[1], nb, ldsoff[1]); }                 \
    if (DOMFMA) {                                                                          \
        __builtin_amdgcn_s_setprio(1);                                                     \
        acc[2][0] = MF32(afhi[(P)^1][0], bfr[(P)^1][0], acc[2][0]);                        \
        acc[2][1] = MF32(afhi[(P)^1][0], bfr[(P)^1][2], acc[2][1]);                        \
        acc[3][0] = MF32(afhi[(P)^1][2], bfr[(P)^1][0], acc[3][0]);                        \
        acc[3][1] = MF32(afhi[(P)^1][2], bfr[(P)^1][2], acc[3][1]);                        \
        acc[2][0] = MF32(afhi[(P)^1][1], bfr[(P)^1][1], acc[2][0]);                        \
        acc[2][1] = MF32(afhi[(P)^1][1], bfr[(P)^1][3], acc[2][1]);                        \
        acc[3][0] = MF32(afhi[(P)^1][3], bfr[(P)^1][1], acc[3][0]);                        \
        acc[3][1] = MF32(afhi[(P)^1][3], bfr[(P)^1][3], acc[3][1]);                        \
        __builtin_amdgcn_s_setprio(0);                                                     \
    }                                                                                      \
} while (0)

// R2 of tile T: read afhi (A row-blocks 2,3); issue DMA 2,3 for tile T+3; advance g;
// MFMA row-blocks 0,1 of tile T; tile-end waitcnt; the only barrier of the tile.
#define R2(BUFC, BUFN, P, DOISS, WAITS) do {                                               \
    const u16* __restrict__ sb = S + (BUFC) * 16384;                                       \
    u16* nb = S + (BUFN) * 16384;                                                          \
    afhi[P][0] = *(const shortx8*)(sb + aBase + 4096 + cA0);                               \
    afhi[P][1] = *(const shortx8*)(sb + aBase + 4096 + cA1);                               \
    afhi[P][2] = *(const shortx8*)(sb + aBase + 6144 + cA0);                               \
    afhi[P][3] = *(const shortx8*)(sb + aBase + 6144 + cA1);                               \
    if (DOISS) {                                                                           \
        ISSUE(g[2], nb, ldsoff[2]); ISSUE(g[3], nb, ldsoff[3]);                            \
        _Pragma("unroll")                                                                  \
        for (int l = 0; l < 4; l++) g[l] += 32;                                            \
    }                                                                                      \
    __builtin_amdgcn_s_setprio(1);                                                         \
    acc[0][0] = MF32(aflo[P][0], bfr[P][0], acc[0][0]);                                    \
    acc[0][1] = MF32(aflo[P][0], bfr[P][2], acc[0][1]);                                    \
    acc[1][0] = MF32(aflo[P][2], bfr[P][0], acc[1][0]);                                    \
    acc[1][1] = MF32(aflo[P][2], bfr[P][2], acc[1][1]);                                    \
    acc[0][0] = MF32(aflo[P][1], bfr[P][1], acc[0][0]);                                    \
    acc[0][1] = MF32(aflo[P][1], bfr[P][3], acc[0][1]);                                    \
    acc[1][0] = MF32(aflo[P][3], bfr[P][1], acc[1][0]);                                    \
    acc[1][1] = MF32(aflo[P][3], bfr[P][3], acc[1][1]);                                    \
    __builtin_amdgcn_s_setprio(0);                                                         \
    WAITS;                                                                                 \
    __builtin_amdgcn_s_barrier();                                                          \
} while (0)

__global__ __launch_bounds__(512, 2)
void gemm256(const u16* __restrict__ At, const u16* __restrict__ Bt,
             const float* __restrict__ bias, float* __restrict__ out,
             int O, int I, int KT) {
    __shared__ u16 S[4 * 16384];          // 128 KiB: 4-buffer ring

    const int tid = threadIdx.x;
    const int nblk_n = O / 256;

    // bijective XCD swizzle
    int bid = blockIdx.x;
    const int nwg = gridDim.x;
    if ((nwg & 7) == 0) {
        const int q = nwg >> 3;
        bid = (bid & 7) * q + (bid >> 3);
    }
    const int mt = bid / nblk_n, nt = bid % nblk_n;

    const int w = tid >> 6, lane = tid & 63;
    const int wm = w >> 2, wn = w & 3;        // 2x4 wave grid; wave owns 128(M) x 64(O)
    const int l31 = lane & 31, l5 = lane >> 5;
    const int sw  = lane & 7;                 // read-side un-swizzle (row&7 == lane&7)

    // frag base offsets (u16 units) within a buffer; row stride 64 u16 (128 B)
    // A row-block i at aBase + i*2048; k-half h chunk = h*2 + l5 (A), 4 + h*2 + l5 (B)
    const int aBase = (wm * 128 + l31) * 64;
    const int bBase = (wn * 64  + l31) * 64;
    const int cA0 = (((0 + l5) ^ sw)) * 8;    // A k-half 0
    const int cA1 = (((2 + l5) ^ sw)) * 8;    // A k-half 1
    const int cB0 = (((4 + l5) ^ sw)) * 8;    // B k-half 0
    const int cB1 = (((6 + l5) ^ sw)) * 8;    // B k-half 1

    // staging: 4 loads/thread/tile; load l covers chunk-slot s = (w*4+l)*64 + lane.
    const u16* g[4];
    int ldsoff[4];
    #pragma unroll
    for (int l = 0; l < 4; l++) {
        const int s   = (w * 4 + l) * 64 + lane;
        const int row = s >> 3;
        const int k   = (s & 7) ^ (row & 7);
        ldsoff[l] = (w * 4 + l) * 512 + lane * 8;      // lane-linear 16B slots (u16 units)
        g[l] = (k < 4) ? (At + (size_t)(mt * 256 + row) * I + k * 8)
                       : (Bt + (size_t)(nt * 256 + row) * I + (k - 4) * 8);
    }

    floatx16 acc[4][2];
    #pragma unroll
    for (int i = 0; i < 4; i++)
        #pragma unroll
        for (int j = 0; j < 2; j++)
            #pragma unroll
            for (int r = 0; r < 16; r++)
                acc[i][j][r] = 0.f;

    shortx8 aflo[2][4], afhi[2][4], bfr[2][4];

    // prologue: stage tiles 0,1,2; wait tile 0 (tiles 1,2 stay in flight)
    #pragma unroll
    for (int p = 0; p < 3; p++) {
        u16* sb = &S[p * 16384];
        #pragma unroll
        for (int l = 0; l < 4; l++)
            ISSUE(g[l], sb, ldsoff[l]);
        #pragma unroll
        for (int l = 0; l < 4; l++) g[l] += 32;
    }
    asm volatile("s_waitcnt vmcnt(8)" ::: "memory");
    __builtin_amdgcn_s_barrier();

    // tile 0 (buf 0, parity 0): fills the register pipeline; no hi-phase MFMA yet
    R1(0, 3, 0, 1, 0);
    R2(0, 3, 0, 1, VM8L);

    // steady state: tiles 1..KT-4 in 4-tile unroll (parities 1,0,1,0; bufs 1,2,3,0)
    const int iters = (KT - 4) >> 2;
    for (int it = 0; it < iters; ++it) {
        R1(1, 0, 1, 1, 1); R2(1, 0, 1, 1, VM8L);
        R1(2, 1, 0, 1, 1); R2(2, 1, 0, 1, VM8L);
        R1(3, 2, 1, 1, 1); R2(3, 2, 1, 1, VM8L);
        R1(0, 3, 0, 1, 1); R2(0, 3, 0, 1, VM8L);
    }

    // epilogue tiles KT-3, KT-2, KT-1 (parities 1,0,1; bufs 1,2,3): drain
    R1(1, 0, 1, 0, 1); R2(1, 0, 1, 0, VM4L);
    R1(2, 1, 0, 0, 1); R2(2, 1, 0, 0, VM0L);
    R1(3, 2, 1, 0, 1); R2(3, 2, 1, 0, (void)0);

    // final hi row-blocks of last tile (parity 1), register-only
    __builtin_amdgcn_s_setprio(1);
    acc[2][0] = MF32(afhi[1][0], bfr[1][0], acc[2][0]);
    acc[2][1] = MF32(afhi[1][0], bfr[1][2], acc[2][1]);
    acc[3][0] = MF32(afhi[1][2], bfr[1][0], acc[3][0]);
    acc[3][1] = MF32(afhi[1][2], bfr[1][2], acc[3][1]);
    acc[2][0] = MF32(afhi[1][1], bfr[1][1], acc[2][0]);
    acc[2][1] = MF32(afhi[1][1], bfr[1][3], acc[2][1]);
    acc[3][0] = MF32(afhi[1][3], bfr[1][1], acc[3][0]);
    acc[3][1] = MF32(afhi[1][3], bfr[1][3], acc[3][1]);
    __builtin_amdgcn_s_setprio(0);

    // epilogue: 32x32 C/D map: col = lane&31, row = (reg&3) + 8*(reg>>2) + 4*(lane>>5)
    #pragma unroll
    for (int j = 0; j < 2; j++) {
        const int colb = nt * 256 + wn * 64 + j * 32 + l31;
        const float bv = bias[colb];
        #pragma unroll
        for (int i = 0; i < 4; i++) {
            const int rowb = mt * 256 + wm * 128 + i * 32 + l5 * 4;
            #pragma unroll
            for (int reg = 0; reg < 16; reg++) {
                const int r = (reg & 3) + 8 * (reg >> 2);
                out[(size_t)(rowb + r) * O + colb] = acc[i][j][reg] + bv;
            }
        }
    }
}

// ============ 128x128 single-buffer GEMM (shape fallback, proven 130 us) ============
__global__ __launch_bounds__(THREADS, 2)
void gemm_bf16(const u16* __restrict__ At, const u16* __restrict__ Bt,
               const float* __restrict__ bias, float* __restrict__ out,
               int O, int I, int KT) {
    __shared__ u16 As[CHUNK];
    __shared__ u16 Bs[CHUNK];

    const int tid = threadIdx.x;
    const int nblk_n = O / TILE;
    const int mt = blockIdx.x / nblk_n;
    const int nt = blockIdx.x % nblk_n;
    const int w = tid >> 6, lane = tid & 63;
    const int wm = w >> 1, wn = w & 1;
    const int l15 = lane & 15, l4 = lane >> 4;
    const int sw  = l15 & 7;

    const int sr = tid >> 3;
    const int sc = (tid & 7) ^ (sr & 7);

    floatx4 acc[4][4];
    #pragma unroll
    for (int i = 0; i < 4; i++)
        #pragma unroll
        for (int j = 0; j < 4; j++)
            acc[i][j] = (floatx4){0.f, 0.f, 0.f, 0.f};

    const u16* gaBase = At + ((size_t)(mt * TILE) + sr) * I + sc * 8;
    const u16* gbBase = Bt + ((size_t)(nt * TILE) + sr) * I + sc * 8;

    for (int kt = 0; kt < KT; kt++) {
        const u16* ga = gaBase + kt * BK;
        const u16* gb = gbBase + kt * BK;
        __syncthreads();
        #pragma unroll
        for (int it = 0; it < 4; it++) {
            const int ldsOff = it * 2048 + tid * 8;
            const size_t gOff = (size_t)(it * 32) * I;
            ISSUE(ga + gOff, As, ldsOff);
            ISSUE(gb + gOff, Bs, ldsOff);
        }
        __syncthreads();

        #pragma unroll
        for (int kss = 0; kss < 2; kss++) {
            shortx8 af[4], bfr2[4];
            #pragma unroll
            for (int i = 0; i < 4; i++)
                af[i] = *(const shortx8*)(&As[(wm * 64 + i * 16 + l15) * BK + ((kss * 4 + l4) ^ sw) * 8]);
            #pragma unroll
            for (int j = 0; j < 4; j++)
                bfr2[j] = *(const shortx8*)(&Bs[(wn * 64 + j * 16 + l15) * BK + ((kss * 4 + l4) ^ sw) * 8]);
            #pragma unroll
            for (int i = 0; i < 4; i++)
                #pragma unroll
                for (int j = 0; j < 4; j++)
                    acc[i][j] = __builtin_amdgcn_mfma_f32_16x16x32_bf16(af[i], bfr2[j], acc[i][j], 0, 0, 0);
        }
    }

    #pragma unroll
    for (int j = 0; j < 4; j++) {
        int col  = nt * TILE + wn * 64 + j * 16 + l15;
        float bv = bias[col];
        #pragma unroll
        for (int i = 0; i < 4; i++) {
            int rowb = mt * TILE + wm * 64 + i * 16 + l4 * 4;
            #pragma unroll
            for (int r = 0; r < 4; r++)
                out[(size_t)(rowb + r) * O + col] = acc[i][j][r] + bv;
        }
    }
}

// ======================= fallback (fused) if ws too small =======================
#define LDA 72
__global__ __launch_bounds__(THREADS, 2)
void wql_fused(const float* __restrict__ x, const int* __restrict__ pw,
               const float* __restrict__ scale, const int* __restrict__ pzp,
               const float* __restrict__ bias, float* __restrict__ out,
               int M, int O, int I, int ng)
{
    __shared__ unsigned short As[TILE * LDA];
    __shared__ unsigned short Bs[TILE * LDA];
    const int tid = threadIdx.x;
    const int nblk_n = O / TILE;
    const int mt = blockIdx.x / nblk_n, nt = blockIdx.x % nblk_n;
    const int w = tid >> 6, lane = tid & 63;
    const int wm = w >> 1, wn = w & 1;
    const int l15 = lane & 15, l4 = lane >> 4;
    const int pw_rowlen = I / 8, zp_rowlen = (ng + 7) / 8, GS = I / ng;

    floatx4 acc[4][4];
    #pragma unroll
    for (int i = 0; i < 4; i++)
        #pragma unroll
        for (int j = 0; j < 4; j++) acc[i][j] = (floatx4){0.f, 0.f, 0.f, 0.f};

    const int nk = I / BK;
    for (int kt = 0; kt < nk; kt++) {
        __syncthreads();
        #pragma unroll
        for (int it = 0; it < 8; it++) {
            int f = tid + it * THREADS;
            int row = f >> 4, seg = f & 15;
            const float4 v = *(const float4*)(x + (size_t)(mt * TILE + row) * I + kt * BK + seg * 4);
            ushortx4 b;
            b.x = f2bf(v.x); b.y = f2bf(v.y); b.z = f2bf(v.z); b.w = f2bf(v.w);
            *(ushortx4*)(&As[row * LDA + seg * 4]) = b;
        }
        const int g = (kt * BK) / GS;
        #pragma unroll
        for (int it = 0; it < 4; it++) {
            int e = tid + it * THREADS;
            int row = e >> 3, c = e & 7;
            int o = nt * TILE + row;
            int wq = pw[(size_t)o * pw_rowlen + kt * (BK / 8) + c];
            float s = scale[o * ng + g];
            int zpw = pzp[o * zp_rowlen + (g >> 3)];
            int zp = (zpw >> ((g & 7) * 4)) & 15;
            shortx8 b;
            #pragma unroll
            for (int j = 0; j < 8; j++) {
                int nib = (wq >> (4 * j)) & 15;
                b[j] = (short)f2bf((float)(nib - zp) * s);
            }
            *(shortx8*)(&Bs[row * LDA + c * 8]) = b;
        }
        __syncthreads();
        #pragma unroll
        for (int kss = 0; kss < 2; kss++) {
            shortx8 af[4], bfr2[4];
            #pragma unroll
            for (int i = 0; i < 4; i++)
                af[i] = *(const shortx8*)(&As[(wm * 64 + i * 16 + l15) * LDA + kss * 32 + l4 * 8]);
            #pragma unroll
            for (int j = 0; j < 4; j++)
                bfr2[j] = *(const shortx8*)(&Bs[(wn * 64 + j * 16 + l15) * LDA + kss * 32 + l4 * 8]);
            #pragma unroll
            for (int i = 0; i < 4; i++)
                #pragma unroll
                for (int j = 0; j < 4; j++)
                    acc[i][j] = __builtin_amdgcn_mfma_f32_16x16x32_bf16(af[i], bfr2[j], acc[i][j], 0, 0, 0);
        }
    }
    #pragma unroll
    for (int j = 0; j < 4; j++) {
        int col = nt * TILE + wn * 64 + j * 16 + l15;
        float bv = bias[col];
        #pragma unroll
        for (int i = 0; i < 4; i++) {
            int rowb = mt * TILE + wm * 64 + i * 16 + l4 * 4;
            #pragma unroll
            for (int r = 0; r < 4; r++)
                out[(size_t)(rowb + r) * O + col] = acc[i][j][r] + bv;
        }
    }
}

extern "C" void kernel_launch(void* const* d_in, const int* in_sizes, int n_in,
                              void* d_out, int out_size, void* d_ws, size_t ws_size,
                              hipStream_t stream) {
    const float* x     = (const float*)d_in[0];
    const int*   pw    = (const int*)d_in[1];
    const float* scale = (const float*)d_in[2];
    const int*   pzp   = (const int*)d_in[3];
    const float* bias  = (const float*)d_in[4];
    float*       out   = (float*)d_out;

    const int O  = in_sizes[4];                   // 4096
    const int ng = in_sizes[2] / O;               // 32
    const int I  = (in_sizes[1] / O) * 8;         // 4096
    const int M  = in_sizes[0] / I;               // 4096
    int lsSeg = 0; { int v = I >> 3; while ((1 << lsSeg) < v) lsSeg++; }
    int lsG = 0;   { int v = (I / ng) >> 3; while ((1 << lsG) < v) lsG++; }

    const size_t need = ((size_t)M * I + (size_t)O * I) * sizeof(u16);  // 64 MB
    if (ws_size >= need) {
        u16* At = (u16*)d_ws;
        u16* Bt = At + (size_t)M * I;
        prep_kernel<<<dim3(2048), THREADS, 0, stream>>>(x, pw, scale, pzp, At, Bt, M, O, I, ng, lsSeg, lsG);
        const int KT32 = I / 32;
        const bool ok256 = (M % 256 == 0) && (O % 256 == 0) && (I % 128 == 0) && (KT32 >= 8) && ((KT32 & 3) == 0);
        if (ok256) {
            gemm256<<<dim3((M / 256) * (O / 256)), 512, 0, stream>>>(At, Bt, bias, out, O, I, KT32);
        } else {
            gemm_bf16<<<dim3((M / TILE) * (O / TILE)), THREADS, 0, stream>>>(At, Bt, bias, out, O, I, I / BK);
        }
    } else {
        wql_fused<<<dim3((M / TILE) * (O / TILE)), THREADS, 0, stream>>>(x, pw, scale, pzp, bias, out, M, O, I, ng);
    }
}